// Round 2
// baseline (1891.048 us; speedup 1.0000x reference)
//
#include <hip/hip_runtime.h>
#include <hip/hip_bf16.h>

// LSTMCellModel: only seq row 1023 feeds the output => batch-1 recurrence.
// ws layout (floats): A[128][2][4096] | Hh[128][1024] | htmp[1024] | h0[1024] | c[1024]
// total ~4.75 MB.

#define IN_DIM 512
#define HDIM   1024
#define G4     4096
#define NSTEP  128
#define ODIM   1000

__device__ __forceinline__ float sigf(float x) { return 1.f / (1.f + __expf(-x)); }

__global__ void k_init(float* __restrict__ h0, float* __restrict__ c) {
    int i = threadIdx.x + blockIdx.x * blockDim.x;
    if (i < HDIM) { h0[i] = 0.f; c[i] = 0.f; }
}

// A[t][cell][row] = sum_k w_ih[row,k] * 255*x[t,1023,k] + b_ih[row] + b_hh[row]
// grid 512 WGs x 256 thr; WG = 16 consecutive rows of the combined 8192-row space.
__global__ void k_prep(const float* __restrict__ x,
                       const float* __restrict__ wih1, const float* __restrict__ bih1,
                       const float* __restrict__ bhh1,
                       const float* __restrict__ wih2, const float* __restrict__ bih2,
                       const float* __restrict__ bhh2,
                       float* __restrict__ A) {
    __shared__ float Wsh[16][IN_DIM + 1];  // +1 pad: break bank aliasing
    __shared__ float xs[IN_DIM];
    const int R0   = blockIdx.x * 16;
    const int cell = R0 >> 12;        // /4096 (blocks never straddle cells)
    const int row0 = R0 & 4095;
    const float* __restrict__ wih = cell ? wih2 : wih1;
    const float* __restrict__ bih = cell ? bih2 : bih1;
    const float* __restrict__ bhh = cell ? bhh2 : bhh1;
    const int tid = threadIdx.x;

    // stage 16x512 weight block, coalesced float4
    for (int idx = tid; idx < 16 * (IN_DIM / 4); idx += 256) {
        int r  = idx / (IN_DIM / 4);
        int c4 = idx % (IN_DIM / 4);
        float4 v = ((const float4*)(wih + (size_t)(row0 + r) * IN_DIM))[c4];
        Wsh[r][c4 * 4 + 0] = v.x; Wsh[r][c4 * 4 + 1] = v.y;
        Wsh[r][c4 * 4 + 2] = v.z; Wsh[r][c4 * 4 + 3] = v.w;
    }
    const int row_local = tid >> 4;   // 0..15
    const int lane16    = tid & 15;
    const float bias = bih[row0 + row_local] + bhh[row0 + row_local];

    for (int t = 0; t < NSTEP; ++t) {
        __syncthreads();  // covers W staging (t==0) and xs reuse (t>0)
        for (int idx = tid; idx < IN_DIM; idx += 256)
            xs[idx] = x[(size_t)t * HDIM * IN_DIM + (size_t)1023 * IN_DIM + idx] * 255.f;
        __syncthreads();
        float p = 0.f;
#pragma unroll
        for (int m = 0; m < 32; ++m)
            p += Wsh[row_local][lane16 + 16 * m] * xs[lane16 + 16 * m];
        p += __shfl_xor(p, 8); p += __shfl_xor(p, 4);
        p += __shfl_xor(p, 2); p += __shfl_xor(p, 1);
        if (lane16 == 0)
            A[((size_t)t * 2 + cell) * G4 + row0 + row_local] = p + bias;
    }
}

// One LSTM cell phase: gates = Arow + Whh @ h_in ; update c, h_out.
// grid 256 WGs x 256 thr; WG owns j0..j0+3 (16 gate rows, one gate per wave).
__global__ void k_cell(const float* __restrict__ Whh, const float* __restrict__ Arow,
                       const float* __restrict__ h_in, float* __restrict__ h_out,
                       float* __restrict__ c) {
    __shared__ float hs[HDIM];
    __shared__ float gs[16];
    const int tid = threadIdx.x;
    ((float4*)hs)[tid] = ((const float4*)h_in)[tid];
    __syncthreads();
    const int q    = tid >> 6;   // wave id == gate (i,f,g,o)
    const int lane = tid & 63;
    const int j0   = blockIdx.x * 4;
#pragma unroll
    for (int k = 0; k < 4; ++k) {
        const int row = q * HDIM + j0 + k;
        const float* __restrict__ wr = Whh + (size_t)row * HDIM;
        float p = 0.f;
#pragma unroll
        for (int m = 0; m < 16; ++m)
            p += wr[lane + 64 * m] * hs[lane + 64 * m];
        p += __shfl_down(p, 32); p += __shfl_down(p, 16); p += __shfl_down(p, 8);
        p += __shfl_down(p, 4);  p += __shfl_down(p, 2);  p += __shfl_down(p, 1);
        if (lane == 0) gs[q * 4 + k] = p + Arow[row];
    }
    __syncthreads();
    if (tid < 4) {
        const int j = j0 + tid;
        const float iv = gs[tid], fv = gs[4 + tid], gv = gs[8 + tid], ov = gs[12 + tid];
        const float cv = c[j];
        const float cn = sigf(fv) * cv + sigf(iv) * tanhf(gv);
        c[j] = cn;
        h_out[j] = sigf(ov) * tanhf(cn);
    }
}

// out[t][o] = Hh[t] . wfc[o] + bfc[o], fp32 store. grid 125 WGs x 256 thr (8 o per WG).
__global__ void k_fc(const float* __restrict__ Hh, const float* __restrict__ wfc,
                     const float* __restrict__ bfc, float* __restrict__ out) {
    __shared__ float Wf[8][HDIM];
    const int tid = threadIdx.x;
    const int o0  = blockIdx.x * 8;
    for (int idx = tid; idx < 8 * (HDIM / 4); idx += 256) {
        int r  = idx >> 8;         // /256
        int c4 = idx & 255;
        float4 v = ((const float4*)(wfc + (size_t)(o0 + r) * HDIM))[c4];
        Wf[r][c4 * 4 + 0] = v.x; Wf[r][c4 * 4 + 1] = v.y;
        Wf[r][c4 * 4 + 2] = v.z; Wf[r][c4 * 4 + 3] = v.w;
    }
    __syncthreads();
    const int ol = tid >> 5, lane32 = tid & 31;
    const float bias = bfc[o0 + ol];
    for (int t = 0; t < NSTEP; ++t) {
        const float* __restrict__ hv = Hh + (size_t)t * HDIM;
        float p = 0.f;
#pragma unroll
        for (int m = 0; m < 32; ++m)
            p += hv[lane32 + 32 * m] * Wf[ol][lane32 + 32 * m];
        p += __shfl_xor(p, 16); p += __shfl_xor(p, 8); p += __shfl_xor(p, 4);
        p += __shfl_xor(p, 2);  p += __shfl_xor(p, 1);
        if (lane32 == 0)
            out[t * ODIM + o0 + ol] = p + bias;
    }
}

extern "C" void kernel_launch(void* const* d_in, const int* in_sizes, int n_in,
                              void* d_out, int out_size, void* d_ws, size_t ws_size,
                              hipStream_t stream) {
    const float* x    = (const float*)d_in[0];
    const float* wih1 = (const float*)d_in[1];
    const float* whh1 = (const float*)d_in[2];
    const float* bih1 = (const float*)d_in[3];
    const float* bhh1 = (const float*)d_in[4];
    const float* wih2 = (const float*)d_in[5];
    const float* whh2 = (const float*)d_in[6];
    const float* bih2 = (const float*)d_in[7];
    const float* bhh2 = (const float*)d_in[8];
    const float* wfc  = (const float*)d_in[9];
    const float* bfc  = (const float*)d_in[10];
    float* out = (float*)d_out;

    float* A    = (float*)d_ws;                   // 128*2*4096
    float* Hh   = A + (size_t)NSTEP * 2 * G4;     // 128*1024
    float* htmp = Hh + (size_t)NSTEP * HDIM;      // 1024
    float* h0   = htmp + HDIM;                    // 1024
    float* cbuf = h0 + HDIM;                      // 1024

    hipLaunchKernelGGL(k_init, dim3(4), dim3(256), 0, stream, h0, cbuf);
    hipLaunchKernelGGL(k_prep, dim3(512), dim3(256), 0, stream,
                       x, wih1, bih1, bhh1, wih2, bih2, bhh2, A);

    const float* hin = h0;
    for (int t = 0; t < NSTEP; ++t) {
        hipLaunchKernelGGL(k_cell, dim3(256), dim3(256), 0, stream,
                           whh1, A + ((size_t)t * 2 + 0) * G4, hin, htmp, cbuf);
        hipLaunchKernelGGL(k_cell, dim3(256), dim3(256), 0, stream,
                           whh2, A + ((size_t)t * 2 + 1) * G4, htmp,
                           Hh + (size_t)t * HDIM, cbuf);
        hin = Hh + (size_t)t * HDIM;
    }
    hipLaunchKernelGGL(k_fc, dim3(125), dim3(256), 0, stream, Hh, wfc, bfc, out);
}